// Round 1
// 123.103 us; speedup vs baseline: 1.0034x; 1.0034x over previous
//
#include <hip/hip_runtime.h>
#include <hip/hip_bf16.h>

// Problem constants: B=8, T=32768, F_IN=64, N=64, F=64, HID=32
//
// Single fused kernel (no workspace, no second launch):
//   per block of TILE outputs, recompute the MLP over [t0-WWIN, t0+TILE)
//   (halo recompute: +25% x reads), keep u and the feedthrough yd entirely
//   in LDS, build the 256 FIR taps in-block, apply the causal FIR, write y once.
#define BB   8
#define TT   32768
#define FIN  64
#define HIDN 32
#define NST  64
#define FFD  64
#define WWIN 256          // FIR window: A^256 ~ 1e-45 -> exact truncation in fp32
#define TILE 1024         // conv outputs per block
#define NTHR 512          // 8 waves
#define ROWS (WWIN + TILE)   // 1280 rows of u computed per block
#define RPW  (ROWS / 8)      // 160 rows per wave
#define TPW  (RPW / 16)      // 10 MFMA tiles (of 16 rows) per wave

typedef __attribute__((ext_vector_type(8))) short short8;
typedef __attribute__((ext_vector_type(4))) float f32x4;

static __device__ __forceinline__ unsigned short f2bf(float f) {
    unsigned int u = __builtin_bit_cast(unsigned int, f);
    unsigned int lsb = (u >> 16) & 1u;
    u += 0x7fffu + lsb;                 // round-to-nearest-even
    return (unsigned short)(u >> 16);
}

static __device__ __forceinline__ float dot8(float4 a0, float4 a1, float4 b0, float4 b1) {
    return a0.x*b0.x + a0.y*b0.y + a0.z*b0.z + a0.w*b0.w
         + a1.x*b1.x + a1.y*b1.y + a1.z*b1.z + a1.w*b1.w;
}

// Pack 8 fp32 -> short8 of bf16 via v_cvt_pk_bf16_f32 (RNE, matches f2bf bitwise)
static __device__ __forceinline__ short8 pack_bf8(float4 a, float4 b) {
    union { short8 s8; __hip_bfloat162 b2[4]; } u;
    u.b2[0] = __float22bfloat162_rn({a.x, a.y});
    u.b2[1] = __float22bfloat162_rn({a.z, a.w});
    u.b2[2] = __float22bfloat162_rn({b.x, b.y});
    u.b2[3] = __float22bfloat162_rn({b.z, b.w});
    return u.s8;
}

// Grid: 256 blocks x 512 threads. Block b,t0 computes y[b, t0 : t0+TILE).
// MFMA operand order: D = W1frag * xfrag, so C/D holds D[n=quad*4+r][t=lane&15].
__global__ __launch_bounds__(NTHR) void fused_kernel(
    const float* __restrict__ x, const float* __restrict__ W1,
    const float* __restrict__ b1, const float* __restrict__ W2,
    const float* __restrict__ b2, const float* __restrict__ Lraw,
    const float* __restrict__ P, const float* __restrict__ Wu,
    const float* __restrict__ C, const float* __restrict__ Dv,
    const float* __restrict__ b_y, float* __restrict__ y)
{
    __shared__ __align__(16) uint4 fragLDS[4 * 64];      // 4 KB: W1 bf16 fragments
    __shared__ float pu[32 * 8], pd[32 * 8], pc[16];
    __shared__ __align__(16) float wuF[32], wdF[32];
    __shared__ float cucd[2];
    __shared__ float spv[NST], cpv[NST];
    __shared__ __align__(16) float us[ROWS];             // u for [t0-WWIN, t0+TILE)
    __shared__ __align__(16) float yv[TILE];             // feedthrough yd for [t0, t0+TILE)
    __shared__ __align__(16) float Ks[WWIN];             // FIR taps
    __shared__ __align__(16) float ypart[TILE];          // high-tap partials

    int tid = threadIdx.x;
    int b   = blockIdx.x >> 5;                // 32 blocks per sequence (T/TILE)
    int t0  = (blockIdx.x & 31) * TILE;

    // --- per-block prep, phase A ---------------------------------------
    if (tid < 256) {
        // W1 -> bf16 fragment. frag f = khalf + 2*ntile.
        // lane holds W1[k][n] with n=(lane&15)+16*ntile, k=khalf*32+(lane>>4)*8+j
        int f     = tid >> 6;
        int lane_ = tid & 63;
        int khalf = f & 1, ntile = f >> 1;
        int qd    = lane_ >> 4;
        int nn    = (lane_ & 15) + ntile * 16;
        unsigned short h8[8];
#pragma unroll
        for (int j = 0; j < 8; ++j) {
            int k = khalf * 32 + qd * 8 + j;
            h8[j] = f2bf(W1[k * HIDN + nn]);
        }
        fragLDS[tid] = make_uint4(
            (unsigned int)h8[0] | ((unsigned int)h8[1] << 16),
            (unsigned int)h8[2] | ((unsigned int)h8[3] << 16),
            (unsigned int)h8[4] | ((unsigned int)h8[5] << 16),
            (unsigned int)h8[6] | ((unsigned int)h8[7] << 16));

        // folded readouts, 8-way partials: h = tid>>3, part = tid&7
        int h = tid >> 3, part = tid & 7;
        const float4* w2p = (const float4*)(W2 + h * FFD + part * 8);
        float4 wa = w2p[0], wb = w2p[1];
        float4 ua = *(const float4*)(Wu + part * 8);
        float4 ub = *(const float4*)(Wu + part * 8 + 4);
        float4 da = *(const float4*)(Dv + part * 8);
        float4 db = *(const float4*)(Dv + part * 8 + 4);
        pu[tid] = dot8(wa, wb, ua, ub);
        pd[tid] = dot8(wa, wb, da, db);
        if (tid < 8) {
            float4 ba = *(const float4*)(b2 + tid * 8);
            float4 bb = *(const float4*)(b2 + tid * 8 + 4);
            float4 u2a = *(const float4*)(Wu + tid * 8);
            float4 u2b = *(const float4*)(Wu + tid * 8 + 4);
            pc[tid] = dot8(ba, bb, u2a, u2b);
        } else if (tid < 16) {
            int p = tid - 8;
            float4 ba = *(const float4*)(b2 + p * 8);
            float4 bb = *(const float4*)(b2 + p * 8 + 4);
            float4 d2a = *(const float4*)(Dv + p * 8);
            float4 d2b = *(const float4*)(Dv + p * 8 + 4);
            pc[tid] = dot8(ba, bb, d2a, d2b);
        }
    }
    if (tid < NST) {
        float raw = Lraw[tid];
        spv[tid] = fmaxf(raw, 0.f) + log1pf(expf(-fabsf(raw)));  // stable softplus
        cpv[tid] = C[tid] * P[tid];
    }
    __syncthreads();

    // --- phase B: finalize folds + FIR taps ----------------------------
    if (tid < 32) {
        float s = 0.f;
#pragma unroll
        for (int p = 0; p < 8; ++p) s += pu[tid * 8 + p];
        wuF[tid] = s;
    } else if (tid < 64) {
        int h = tid - 32;
        float s = 0.f;
#pragma unroll
        for (int p = 0; p < 8; ++p) s += pd[h * 8 + p];
        wdF[h] = s;
    } else if (tid == 64) {
        float s = 0.f;
#pragma unroll
        for (int p = 0; p < 8; ++p) s += pc[p];
        cucd[0] = s;
    } else if (tid == 65) {
        float s = 0.f;
#pragma unroll
        for (int p = 8; p < 16; ++p) s += pc[p];
        cucd[1] = s + b_y[0];
    }
    if (tid < WWIN) {           // FIR taps: K[j] = sum_n cp[n] * exp(-sp[n]*j)
        float jf = (float)tid;
        float acc = 0.f;
#pragma unroll 4
        for (int n = 0; n < NST; ++n) acc += cpv[n] * __expf(-spv[n] * jf);
        Ks[tid] = acc;
    }
    __syncthreads();

    // --- MLP over ROWS=1280 rows: wave w covers local rows [w*160, w*160+160)
    int lane = tid & 63, wid = tid >> 6;
    int m = lane & 15, quad = lane >> 4;

    short8 bk0n0 = __builtin_bit_cast(short8, fragLDS[0 * 64 + lane]);
    short8 bk1n0 = __builtin_bit_cast(short8, fragLDS[1 * 64 + lane]);
    short8 bk0n1 = __builtin_bit_cast(short8, fragLDS[2 * 64 + lane]);
    short8 bk1n1 = __builtin_bit_cast(short8, fragLDS[3 * 64 + lane]);

    // per-lane readout constants, indexed by n = quad*4 + r (and +16)
    float4 b1A = *(const float4*)&b1[quad * 4];
    float4 b1B = *(const float4*)&b1[16 + quad * 4];
    float4 wuA = *(const float4*)&wuF[quad * 4];
    float4 wuB = *(const float4*)&wuF[16 + quad * 4];
    float4 wdA = *(const float4*)&wdF[quad * 4];
    float4 wdB = *(const float4*)&wdF[16 + quad * 4];
    float cu = cucd[0], cd = cucd[1];

    int wstart = wid * RPW;               // local row base for this wave
    int gbase  = t0 - WWIN + wstart;      // global t of local row wstart (may be <0)
    const float* xb = x + (size_t)b * TT * FIN + quad * 8;

    float4 xv[2][4];
#define LOADT(buf, tt) { int g_ = gbase + (tt) * 16 + m; if (g_ < 0) g_ = 0;      \
        const float* p_ = xb + (size_t)g_ * FIN;                                   \
        (buf)[0] = *(const float4*)(p_);      (buf)[1] = *(const float4*)(p_ + 4); \
        (buf)[2] = *(const float4*)(p_ + 32); (buf)[3] = *(const float4*)(p_ + 36); }

    LOADT(xv[0], 0);
    LOADT(xv[1], 1);

#pragma unroll
    for (int tt = 0; tt < TPW; ++tt) {
        float4 x0 = xv[tt & 1][0], x1 = xv[tt & 1][1];
        float4 x2 = xv[tt & 1][2], x3 = xv[tt & 1][3];
        if (tt + 2 < TPW) LOADT(xv[tt & 1], tt + 2);

        short8 a0 = pack_bf8(x0, x1);   // x[t][k], khalf 0
        short8 a1 = pack_bf8(x2, x3);   // khalf 1

        f32x4 acc0 = {0.f, 0.f, 0.f, 0.f};
        f32x4 acc1 = {0.f, 0.f, 0.f, 0.f};
        // D = W1^T-frag (as A) * x-frag (as B): D[n][t], n=quad*4+r, t=lane&15
        acc0 = __builtin_amdgcn_mfma_f32_16x16x32_bf16(bk0n0, a0, acc0, 0, 0, 0);
        acc0 = __builtin_amdgcn_mfma_f32_16x16x32_bf16(bk1n0, a1, acc0, 0, 0, 0);
        acc1 = __builtin_amdgcn_mfma_f32_16x16x32_bf16(bk0n1, a0, acc1, 0, 0, 0);
        acc1 = __builtin_amdgcn_mfma_f32_16x16x32_bf16(bk1n1, a1, acc1, 0, 0, 0);

        float ut = 0.f, yt = 0.f, h;
        h = fmaxf(acc0[0] + b1A.x, 0.f); ut += h * wuA.x; yt += h * wdA.x;
        h = fmaxf(acc0[1] + b1A.y, 0.f); ut += h * wuA.y; yt += h * wdA.y;
        h = fmaxf(acc0[2] + b1A.z, 0.f); ut += h * wuA.z; yt += h * wdA.z;
        h = fmaxf(acc0[3] + b1A.w, 0.f); ut += h * wuA.w; yt += h * wdA.w;
        h = fmaxf(acc1[0] + b1B.x, 0.f); ut += h * wuB.x; yt += h * wdB.x;
        h = fmaxf(acc1[1] + b1B.y, 0.f); ut += h * wuB.y; yt += h * wdB.y;
        h = fmaxf(acc1[2] + b1B.z, 0.f); ut += h * wuB.z; yt += h * wdB.z;
        h = fmaxf(acc1[3] + b1B.w, 0.f); ut += h * wuB.w; yt += h * wdB.w;

        // reduce over the 4 quad-groups (n blocks of 4): 2-level tree
        ut += __shfl_xor(ut, 16); ut += __shfl_xor(ut, 32);
        yt += __shfl_xor(yt, 16); yt += __shfl_xor(yt, 32);

        if (lane < 16) {                 // all lanes hold full sums; t = lane
            int local = wstart + tt * 16 + lane;
            int g = gbase + tt * 16 + lane;
            us[local] = (g >= 0) ? (ut + cu) : 0.f;     // u (zero left of sequence)
            if (local >= WWIN) yv[local - WWIN] = yt + cd;   // feedthrough yd
        }
    }
#undef LOADT
    __syncthreads();

    // --- FIR: y[t] = yd[t] + sum_{j<WWIN} K[j]*u[t-j] --------------------
    // 1024 outputs, 512 threads: half 0 does taps [0,128) seeded with yd,
    // half 1 does taps [128,256) into ypart; then half 0 combines + stores.
    {
        int half = tid >> 8;             // 0 or 1
        int q    = tid & 255;
        int o    = q * 4;                // output local index (4 per thread)
        int base = WWIN + o;
        float a0, a1, a2, a3;
        if (half == 0) {
            float4 y4 = *(const float4*)&yv[o];
            a0 = y4.x; a1 = y4.y; a2 = y4.z; a3 = y4.w;
        } else {
            a0 = a1 = a2 = a3 = 0.f;
        }
        int j0 = half * 128;
#pragma unroll 8
        for (int j = j0; j < j0 + 128; j += 4) {
            float4 kk = *(const float4*)&Ks[j];
            float4 ua = *(const float4*)&us[base - j - 4];
            float4 ux = *(const float4*)&us[base - j];
            a0 += kk.x * ux.x + kk.y * ua.w + kk.z * ua.z + kk.w * ua.y;
            a1 += kk.x * ux.y + kk.y * ux.x + kk.z * ua.w + kk.w * ua.z;
            a2 += kk.x * ux.z + kk.y * ux.y + kk.z * ux.x + kk.w * ua.w;
            a3 += kk.x * ux.w + kk.y * ux.z + kk.z * ux.y + kk.w * ux.x;
        }
        if (half == 1) *(float4*)&ypart[o] = make_float4(a0, a1, a2, a3);
        __syncthreads();
        if (half == 0) {
            float4 p4 = *(const float4*)&ypart[o];
            size_t oidx = (size_t)b * TT + t0 + o;
            *(float4*)&y[oidx] = make_float4(a0 + p4.x, a1 + p4.y, a2 + p4.z, a3 + p4.w);
        }
    }
}

extern "C" void kernel_launch(void* const* d_in, const int* in_sizes, int n_in,
                              void* d_out, int out_size, void* d_ws, size_t ws_size,
                              hipStream_t stream)
{
    const float* x    = (const float*)d_in[0];
    const float* W1   = (const float*)d_in[1];
    const float* b1   = (const float*)d_in[2];
    const float* W2   = (const float*)d_in[3];
    const float* b2   = (const float*)d_in[4];
    const float* Lraw = (const float*)d_in[5];
    const float* P    = (const float*)d_in[6];
    const float* Wu   = (const float*)d_in[7];
    const float* C    = (const float*)d_in[8];
    const float* Dv   = (const float*)d_in[9];
    const float* b_y  = (const float*)d_in[10];

    float* y = (float*)d_out;
    (void)d_ws; (void)ws_size;   // workspace intentionally unused

    fused_kernel<<<(BB * TT) / TILE, NTHR, 0, stream>>>(
        x, W1, b1, W2, b2, Lraw, P, Wu, C, Dv, b_y, y);
}